// Round 1
// baseline (317.672 us; speedup 1.0000x reference)
//
#include <hip/hip_runtime.h>
#include <hip/hip_bf16.h>
#include <math.h>

// Problem constants (from reference)
constexpr int B  = 8;
constexpr int S  = 2048;
constexpr int H  = 4096;
constexpr int N  = 64;    // N_SLOTS
constexpr int MEM = 16;
constexpr int RH = 256;
constexpr int H4 = H / 4;         // 1024 float4 per row
constexpr int SCHUNK = 16;        // split of S for the mean reduction

// ---------------------------------------------------------------------------
// K1: partial column sums of embeds over S-chunks.
// grid = B * (H4/256) * SCHUNK = 8*4*16 = 512 blocks, 256 threads.
// Coalesced float4 loads; deterministic (no atomics).
// ---------------------------------------------------------------------------
__global__ __launch_bounds__(256) void k_partial(const float* __restrict__ embeds,
                                                 float* __restrict__ partial) {
    int blk = blockIdx.x;
    int c   = blk % SCHUNK;                       // s-chunk
    int ht  = (blk / SCHUNK) % (H4 / 256);        // h-tile
    int b   = blk / (SCHUNK * (H4 / 256));        // batch
    int h4  = ht * 256 + threadIdx.x;

    const float4* src = (const float4*)embeds + (size_t)b * S * H4 + h4;
    int s0 = c * (S / SCHUNK);
    float4 acc = {0.f, 0.f, 0.f, 0.f};
    for (int s = 0; s < S / SCHUNK; ++s) {
        float4 v = src[(size_t)(s0 + s) * H4];
        acc.x += v.x; acc.y += v.y; acc.z += v.z; acc.w += v.w;
    }
    ((float4*)partial)[((size_t)b * SCHUNK + c) * H4 + h4] = acc;
}

// ---------------------------------------------------------------------------
// K2: per-batch routing + slot contribution. One block per batch, 256 threads.
// ---------------------------------------------------------------------------
__global__ __launch_bounds__(256) void k_route(const float* __restrict__ partial,
                                               const float* __restrict__ W1,
                                               const float* __restrict__ b1,
                                               const float* __restrict__ W2,
                                               const float* __restrict__ b2,
                                               const float* __restrict__ gate,
                                               const float* __restrict__ memory,
                                               const int* __restrict__ topk_p,
                                               float* __restrict__ contrib) {
    __shared__ float q[H];            // 16 KB
    __shared__ float hbuf[RH];        // 1 KB
    __shared__ float logits[N];
    __shared__ float wfold[8 * MEM];  // weight_k * sigmoid(gate) for selected slots
    __shared__ int   isel[8];

    int b = blockIdx.x, t = threadIdx.x;
    int K = topk_p[0];
    if (K > 8) K = 8;  // safety clamp (reference uses 4)

    // finish mean: q[h] = (1/S) * sum over chunks
    for (int i = t; i < H; i += 256) {
        float s = 0.f;
        for (int c = 0; c < SCHUNK; ++c)
            s += partial[((size_t)b * SCHUNK + c) * H + i];
        q[i] = s * (1.0f / (float)S);
    }
    __syncthreads();

    // h = relu(W1 @ q + b1) : thread t owns row t of W1 [RH,H]
    {
        const float4* w  = (const float4*)W1 + (size_t)t * H4;
        const float4* q4 = (const float4*)q;
        float acc = b1[t];
        for (int i = 0; i < H4; ++i) {
            float4 wv = w[i];
            float4 qv = q4[i];   // LDS broadcast (same addr all lanes) — free
            acc += wv.x * qv.x + wv.y * qv.y + wv.z * qv.z + wv.w * qv.w;
        }
        hbuf[t] = fmaxf(acc, 0.0f);
    }
    __syncthreads();

    // logits = W2 @ h + b2 : threads 0..63 own one slot each
    if (t < N) {
        const float4* w  = (const float4*)W2 + (size_t)t * (RH / 4);
        const float4* h4p = (const float4*)hbuf;
        float acc = b2[t];
        for (int i = 0; i < RH / 4; ++i) {
            float4 wv = w[i];
            float4 hv = h4p[i];
            acc += wv.x * hv.x + wv.y * hv.y + wv.z * hv.z + wv.w * hv.w;
        }
        logits[t] = acc;  // TEMP == 1.0
    }
    __syncthreads();

    // serial top-K + softmax on thread 0 (N=64, K=4: trivial)
    if (t == 0) {
        bool used[N];
        for (int i = 0; i < N; ++i) used[i] = false;
        float vals[8]; int ids[8];
        for (int k = 0; k < K; ++k) {
            float best = -INFINITY; int bi = 0;
            for (int i = 0; i < N; ++i)
                if (!used[i] && logits[i] > best) { best = logits[i]; bi = i; }
            used[bi] = true; vals[k] = best; ids[k] = bi;
        }
        float m = vals[0];           // sorted descending -> max is first
        float se = 0.f;
        float w[8];
        for (int k = 0; k < K; ++k) { w[k] = expf(vals[k] - m); se += w[k]; }
        float inv = 1.0f / se;
        for (int k = 0; k < K; ++k) {
            isel[k] = ids[k];
            logits[k] = w[k] * inv;   // reuse logits[0..K) to pass weights
        }
    }
    __syncthreads();

    // fold routing weight into sigmoid(gate) per (k, m)
    if (t < K * MEM) {
        int k = t / MEM, m = t % MEM;
        float g = gate[isel[k] * MEM + m];
        wfold[t] = logits[k] / (1.0f + expf(-g));
    }
    __syncthreads();

    // contrib[b][h] = sum_k sum_m wfold[k][m] * memory[slot_k][m][h]
    for (int h4i = t; h4i < H4; h4i += 256) {
        float4 acc = {0.f, 0.f, 0.f, 0.f};
        for (int k = 0; k < K; ++k) {
            const float4* mp = (const float4*)memory + ((size_t)isel[k] * MEM) * H4 + h4i;
            for (int m = 0; m < MEM; ++m) {
                float4 v = mp[(size_t)m * H4];
                float w = wfold[k * MEM + m];
                acc.x += w * v.x; acc.y += w * v.y; acc.z += w * v.z; acc.w += w * v.w;
            }
        }
        ((float4*)contrib)[(size_t)b * H4 + h4i] = acc;
    }
}

// ---------------------------------------------------------------------------
// K3: out[b,s,h] = hidden[b,s,h] + contrib[b,h]   (float4 grid-stride)
// ---------------------------------------------------------------------------
__global__ __launch_bounds__(256) void k_add(const float* __restrict__ hidden,
                                             const float* __restrict__ contrib,
                                             float* __restrict__ out) {
    const size_t total4 = (size_t)B * S * H4;      // 16,777,216
    const size_t stride = (size_t)gridDim.x * blockDim.x;
    const float4* hv4 = (const float4*)hidden;
    const float4* cv4 = (const float4*)contrib;
    float4* o4 = (float4*)out;
    for (size_t i = (size_t)blockIdx.x * blockDim.x + threadIdx.x; i < total4; i += stride) {
        int h4 = (int)(i & (size_t)(H4 - 1));      // H4 = 1024 (pow2)
        int b  = (int)(i >> 21);                   // S*H4 = 2^21 per batch
        float4 hv = hv4[i];
        float4 cv = cv4[(size_t)b * H4 + h4];
        float4 o  = {hv.x + cv.x, hv.y + cv.y, hv.z + cv.z, hv.w + cv.w};
        o4[i] = o;
    }
}

// ---------------------------------------------------------------------------
extern "C" void kernel_launch(void* const* d_in, const int* in_sizes, int n_in,
                              void* d_out, int out_size, void* d_ws, size_t ws_size,
                              hipStream_t stream) {
    const float* embeds = (const float*)d_in[0];
    const float* hidden = (const float*)d_in[1];
    const float* W1     = (const float*)d_in[2];
    const float* b1     = (const float*)d_in[3];
    const float* W2     = (const float*)d_in[4];
    const float* b2     = (const float*)d_in[5];
    const float* gate   = (const float*)d_in[6];
    const float* memory = (const float*)d_in[7];
    const int*   topk   = (const int*)d_in[8];
    float* out = (float*)d_out;

    float* partial = (float*)d_ws;                       // B*SCHUNK*H fp32 = 2 MB
    float* contrib = partial + (size_t)B * SCHUNK * H;   // B*H fp32 = 128 KB

    k_partial<<<dim3(B * (H4 / 256) * SCHUNK), dim3(256), 0, stream>>>(embeds, partial);
    k_route<<<dim3(B), dim3(256), 0, stream>>>(partial, W1, b1, W2, b2, gate, memory,
                                               topk, contrib);
    k_add<<<dim3(2048), dim3(256), 0, stream>>>(hidden, contrib, out);
}

// Round 2
// 218.761 us; speedup vs baseline: 1.4521x; 1.4521x over previous
//
#include <hip/hip_runtime.h>
#include <hip/hip_bf16.h>
#include <math.h>

// Problem constants (from reference)
constexpr int B  = 8;
constexpr int S  = 2048;
constexpr int H  = 4096;
constexpr int N  = 64;    // N_SLOTS
constexpr int MEM = 16;
constexpr int RH = 256;
constexpr int H4 = H / 4;         // 1024 float4 per row
constexpr int SCHUNK = 16;        // split of S for the mean reduction

// ---------------------------------------------------------------------------
// K1: partial column sums of embeds over S-chunks.
// grid = B * (H4/256) * SCHUNK = 512 blocks, 256 threads. Deterministic.
// ---------------------------------------------------------------------------
__global__ __launch_bounds__(256) void k_partial(const float* __restrict__ embeds,
                                                 float* __restrict__ partial) {
    int blk = blockIdx.x;
    int c   = blk % SCHUNK;                       // s-chunk
    int ht  = (blk / SCHUNK) % (H4 / 256);        // h-tile
    int b   = blk / (SCHUNK * (H4 / 256));        // batch
    int h4  = ht * 256 + threadIdx.x;

    const float4* src = (const float4*)embeds + (size_t)b * S * H4 + h4;
    int s0 = c * (S / SCHUNK);
    float4 acc = {0.f, 0.f, 0.f, 0.f};
    for (int s = 0; s < S / SCHUNK; ++s) {
        float4 v = src[(size_t)(s0 + s) * H4];
        acc.x += v.x; acc.y += v.y; acc.z += v.z; acc.w += v.w;
    }
    ((float4*)partial)[((size_t)b * SCHUNK + c) * H4 + h4] = acc;
}

// ---------------------------------------------------------------------------
// K2a: finish mean. grid = 32 blocks x 256 threads = 8192 = B*H4 exactly.
// ---------------------------------------------------------------------------
__global__ __launch_bounds__(256) void k_mean(const float* __restrict__ partial,
                                              float* __restrict__ q) {
    int i  = blockIdx.x * 256 + threadIdx.x;      // 0 .. B*H4-1
    int b  = i / H4;
    int h4 = i % H4;
    const float4* p4 = (const float4*)partial;
    float4 acc = {0.f, 0.f, 0.f, 0.f};
    for (int c = 0; c < SCHUNK; ++c) {
        float4 v = p4[((size_t)b * SCHUNK + c) * H4 + h4];
        acc.x += v.x; acc.y += v.y; acc.z += v.z; acc.w += v.w;
    }
    const float inv = 1.0f / (float)S;
    acc.x *= inv; acc.y *= inv; acc.z *= inv; acc.w *= inv;
    ((float4*)q)[i] = acc;
}

// ---------------------------------------------------------------------------
// K2b: h[b][r] = relu(W1[r] . q[b] + b1[r]).  grid = RH = 256 blocks.
// Each block reads its W1 row once, dots against all 8 batch queries.
// ---------------------------------------------------------------------------
__global__ __launch_bounds__(256) void k_w1(const float* __restrict__ q,
                                            const float* __restrict__ W1,
                                            const float* __restrict__ b1,
                                            float* __restrict__ hws) {
    __shared__ float wred[4][B];   // per-wave partials
    int r = blockIdx.x, t = threadIdx.x;
    const float4* w4 = (const float4*)W1 + (size_t)r * H4;
    const float4* q4 = (const float4*)q;

    float acc[B];
    #pragma unroll
    for (int b = 0; b < B; ++b) acc[b] = 0.f;

    #pragma unroll
    for (int i = 0; i < H4 / 256; ++i) {          // 4 iterations
        int idx = i * 256 + t;
        float4 wv = w4[idx];
        #pragma unroll
        for (int b = 0; b < B; ++b) {
            float4 qv = q4[(size_t)b * H4 + idx];
            acc[b] += wv.x * qv.x + wv.y * qv.y + wv.z * qv.z + wv.w * qv.w;
        }
    }
    // wave-level reduce (wave64)
    #pragma unroll
    for (int b = 0; b < B; ++b) {
        float v = acc[b];
        for (int off = 32; off > 0; off >>= 1) v += __shfl_down(v, off, 64);
        acc[b] = v;
    }
    int wave = t >> 6, lane = t & 63;
    if (lane == 0) {
        #pragma unroll
        for (int b = 0; b < B; ++b) wred[wave][b] = acc[b];
    }
    __syncthreads();
    if (t < B) {
        float s = wred[0][t] + wred[1][t] + wred[2][t] + wred[3][t] + b1[r];
        hws[(size_t)t * RH + r] = fmaxf(s, 0.0f);
    }
}

// ---------------------------------------------------------------------------
// K2c: logits + top-k + softmax + weight folding. One block, 512 threads.
// Outputs: iselws[b*8+k] (int), wfoldws[(b*8+k)*MEM+m] (float).
// ---------------------------------------------------------------------------
__global__ __launch_bounds__(512) void k_gate(const float* __restrict__ hws,
                                              const float* __restrict__ W2,
                                              const float* __restrict__ b2,
                                              const float* __restrict__ gate,
                                              const int* __restrict__ topk_p,
                                              int* __restrict__ iselws,
                                              float* __restrict__ wfoldws) {
    __shared__ float logits[B][N];
    __shared__ float wsel[B][8];
    __shared__ int   isel[B][8];

    int t = threadIdx.x;
    int K = topk_p[0];
    if (K > 8) K = 8;

    // Phase A: logits[b][n], thread = b*64+n
    {
        int b = t >> 6, n = t & 63;
        const float4* w  = (const float4*)W2 + (size_t)n * (RH / 4);
        const float4* h4p = (const float4*)hws + (size_t)b * (RH / 4);
        float acc = b2[n];
        #pragma unroll 8
        for (int i = 0; i < RH / 4; ++i) {
            float4 wv = w[i];
            float4 hv = h4p[i];
            acc += wv.x * hv.x + wv.y * hv.y + wv.z * hv.z + wv.w * hv.w;
        }
        logits[b][n] = acc;   // TEMP == 1.0
    }
    __syncthreads();

    // Phase B: per-batch serial top-K + softmax (threads 0..7)
    if (t < B) {
        bool used[N];
        for (int i = 0; i < N; ++i) used[i] = false;
        float vals[8]; int ids[8];
        for (int k = 0; k < K; ++k) {
            float best = -INFINITY; int bi = 0;
            for (int i = 0; i < N; ++i)
                if (!used[i] && logits[t][i] > best) { best = logits[t][i]; bi = i; }
            used[bi] = true; vals[k] = best; ids[k] = bi;
        }
        float m = vals[0];    // descending order -> first is max
        float se = 0.f, w[8];
        for (int k = 0; k < K; ++k) { w[k] = expf(vals[k] - m); se += w[k]; }
        float inv = 1.0f / se;
        for (int k = 0; k < K; ++k) {
            isel[t][k] = ids[k];
            wsel[t][k] = w[k] * inv;
            iselws[t * 8 + k] = ids[k];
        }
    }
    __syncthreads();

    // Phase C: wfold[b][k][m] = wsel[b][k] * sigmoid(gate[slot][m])
    for (int i = t; i < B * K * MEM; i += 512) {
        int b = i / (K * MEM);
        int k = (i / MEM) % K;
        int m = i % MEM;
        float g = gate[isel[b][k] * MEM + m];
        wfoldws[(b * 8 + k) * MEM + m] = wsel[b][k] / (1.0f + expf(-g));
    }
}

// ---------------------------------------------------------------------------
// K2d: contrib[b][h] = sum_k sum_m wfold[b][k][m] * memory[slot][m][h]
// grid = B * (H4/256) = 32 blocks.
// ---------------------------------------------------------------------------
__global__ __launch_bounds__(256) void k_contrib(const float* __restrict__ memory,
                                                 const int* __restrict__ iselws,
                                                 const float* __restrict__ wfoldws,
                                                 const int* __restrict__ topk_p,
                                                 float* __restrict__ contrib) {
    __shared__ float wf[8 * MEM];
    __shared__ int   sl[8];
    int blk = blockIdx.x, t = threadIdx.x;
    int b  = blk / (H4 / 256);
    int ht = blk % (H4 / 256);
    int K = topk_p[0];
    if (K > 8) K = 8;

    if (t < K * MEM) wf[t] = wfoldws[b * 8 * MEM + (t / MEM) * MEM + (t % MEM)];
    if (t < K) sl[t] = iselws[b * 8 + t];
    __syncthreads();

    int h4 = ht * 256 + t;
    float4 acc = {0.f, 0.f, 0.f, 0.f};
    for (int k = 0; k < K; ++k) {
        const float4* mp = (const float4*)memory + ((size_t)sl[k] * MEM) * H4 + h4;
        for (int m = 0; m < MEM; ++m) {
            float4 v = mp[(size_t)m * H4];
            float w = wf[k * MEM + m];
            acc.x += w * v.x; acc.y += w * v.y; acc.z += w * v.z; acc.w += w * v.w;
        }
    }
    ((float4*)contrib)[(size_t)b * H4 + h4] = acc;
}

// ---------------------------------------------------------------------------
// K3: out[b,s,h] = hidden[b,s,h] + contrib[b,h]   (float4 grid-stride)
// ---------------------------------------------------------------------------
__global__ __launch_bounds__(256) void k_add(const float* __restrict__ hidden,
                                             const float* __restrict__ contrib,
                                             float* __restrict__ out) {
    const size_t total4 = (size_t)B * S * H4;      // 16,777,216
    const size_t stride = (size_t)gridDim.x * blockDim.x;
    const float4* hv4 = (const float4*)hidden;
    const float4* cv4 = (const float4*)contrib;
    float4* o4 = (float4*)out;
    for (size_t i = (size_t)blockIdx.x * blockDim.x + threadIdx.x; i < total4; i += stride) {
        int h4 = (int)(i & (size_t)(H4 - 1));      // H4 = 1024 (pow2)
        int b  = (int)(i >> 21);                   // S*H4 = 2^21 per batch
        float4 hv = hv4[i];
        float4 cv = cv4[(size_t)b * H4 + h4];
        float4 o  = {hv.x + cv.x, hv.y + cv.y, hv.z + cv.z, hv.w + cv.w};
        o4[i] = o;
    }
}

// ---------------------------------------------------------------------------
extern "C" void kernel_launch(void* const* d_in, const int* in_sizes, int n_in,
                              void* d_out, int out_size, void* d_ws, size_t ws_size,
                              hipStream_t stream) {
    const float* embeds = (const float*)d_in[0];
    const float* hidden = (const float*)d_in[1];
    const float* W1     = (const float*)d_in[2];
    const float* b1     = (const float*)d_in[3];
    const float* W2     = (const float*)d_in[4];
    const float* b2     = (const float*)d_in[5];
    const float* gate   = (const float*)d_in[6];
    const float* memory = (const float*)d_in[7];
    const int*   topk   = (const int*)d_in[8];
    float* out = (float*)d_out;

    // workspace layout (floats)
    float* partial = (float*)d_ws;                        // B*SCHUNK*H   = 524288 (2 MB)
    float* q       = partial + (size_t)B * SCHUNK * H;    // B*H          = 32768
    float* hws     = q       + (size_t)B * H;             // B*RH         = 2048
    float* wfoldws = hws     + (size_t)B * RH;            // B*8*MEM      = 1024
    float* contrib = wfoldws + (size_t)B * 8 * MEM;       // B*H          = 32768
    int*   iselws  = (int*)(contrib + (size_t)B * H);     // B*8 ints

    k_partial<<<dim3(B * (H4 / 256) * SCHUNK), dim3(256), 0, stream>>>(embeds, partial);
    k_mean   <<<dim3(B * H4 / 256),            dim3(256), 0, stream>>>(partial, q);
    k_w1     <<<dim3(RH),                      dim3(256), 0, stream>>>(q, W1, b1, hws);
    k_gate   <<<dim3(1),                       dim3(512), 0, stream>>>(hws, W2, b2, gate,
                                                                       topk, iselws, wfoldws);
    k_contrib<<<dim3(B * (H4 / 256)),          dim3(256), 0, stream>>>(memory, iselws,
                                                                       wfoldws, topk, contrib);
    k_add    <<<dim3(2048),                    dim3(256), 0, stream>>>(hidden, contrib, out);
}

// Round 4
// 162.152 us; speedup vs baseline: 1.9591x; 1.3491x over previous
//
#include <hip/hip_runtime.h>
#include <hip/hip_bf16.h>
#include <math.h>

// Problem constants (from reference)
constexpr int B  = 8;
constexpr int S  = 2048;
constexpr int H  = 4096;
constexpr int N  = 64;    // N_SLOTS
constexpr int MEM = 16;
constexpr int RH = 256;
constexpr int H4 = H / 4;         // 1024 float4 per row
constexpr int SCHUNK = 16;        // split of S for the mean reduction

typedef float fx4 __attribute__((ext_vector_type(4)));

__device__ __forceinline__ float4 ntload4(const float4* p) {
    fx4 v = __builtin_nontemporal_load(reinterpret_cast<const fx4*>(p));
    return make_float4(v.x, v.y, v.z, v.w);
}
__device__ __forceinline__ void ntstore4(float4* p, float4 v) {
    fx4 w = {v.x, v.y, v.z, v.w};
    __builtin_nontemporal_store(w, reinterpret_cast<fx4*>(p));
}

// ---------------------------------------------------------------------------
// K1: partial column sums of embeds over S-chunks.
// grid = B * (H4/256) * SCHUNK = 512 blocks, 256 threads. Deterministic.
// embeds is streamed exactly once -> nontemporal loads.
// ---------------------------------------------------------------------------
__global__ __launch_bounds__(256) void k_partial(const float* __restrict__ embeds,
                                                 float* __restrict__ partial) {
    int blk = blockIdx.x;
    int c   = blk % SCHUNK;                       // s-chunk
    int ht  = (blk / SCHUNK) % (H4 / 256);        // h-tile
    int b   = blk / (SCHUNK * (H4 / 256));        // batch
    int h4  = ht * 256 + threadIdx.x;

    const float4* src = (const float4*)embeds + (size_t)b * S * H4 + h4;
    int s0 = c * (S / SCHUNK);
    float4 acc = {0.f, 0.f, 0.f, 0.f};
    #pragma unroll 8
    for (int s = 0; s < S / SCHUNK; ++s) {
        float4 v = ntload4(&src[(size_t)(s0 + s) * H4]);
        acc.x += v.x; acc.y += v.y; acc.z += v.z; acc.w += v.w;
    }
    ((float4*)partial)[((size_t)b * SCHUNK + c) * H4 + h4] = acc;
}

// ---------------------------------------------------------------------------
// K2a: finish mean. grid = 32 blocks x 256 threads = 8192 = B*H4 exactly.
// ---------------------------------------------------------------------------
__global__ __launch_bounds__(256) void k_mean(const float* __restrict__ partial,
                                              float* __restrict__ q) {
    int i  = blockIdx.x * 256 + threadIdx.x;      // 0 .. B*H4-1
    int b  = i / H4;
    int h4 = i % H4;
    const float4* p4 = (const float4*)partial;
    float4 acc = {0.f, 0.f, 0.f, 0.f};
    #pragma unroll
    for (int c = 0; c < SCHUNK; ++c) {
        float4 v = p4[((size_t)b * SCHUNK + c) * H4 + h4];
        acc.x += v.x; acc.y += v.y; acc.z += v.z; acc.w += v.w;
    }
    const float inv = 1.0f / (float)S;
    acc.x *= inv; acc.y *= inv; acc.z *= inv; acc.w *= inv;
    ((float4*)q)[i] = acc;
}

// ---------------------------------------------------------------------------
// K2b: h[b][r] = relu(W1[r] . q[b] + b1[r]).  grid = RH = 256 blocks.
// Each block reads its W1 row once, dots against all 8 batch queries.
// ---------------------------------------------------------------------------
__global__ __launch_bounds__(256) void k_w1(const float* __restrict__ q,
                                            const float* __restrict__ W1,
                                            const float* __restrict__ b1,
                                            float* __restrict__ hws) {
    __shared__ float wred[4][B];   // per-wave partials
    int r = blockIdx.x, t = threadIdx.x;
    const float4* w4 = (const float4*)W1 + (size_t)r * H4;
    const float4* q4 = (const float4*)q;

    float acc[B];
    #pragma unroll
    for (int b = 0; b < B; ++b) acc[b] = 0.f;

    #pragma unroll
    for (int i = 0; i < H4 / 256; ++i) {          // 4 iterations
        int idx = i * 256 + t;
        float4 wv = ntload4(&w4[idx]);            // W1 read exactly once globally
        #pragma unroll
        for (int b = 0; b < B; ++b) {
            float4 qv = q4[(size_t)b * H4 + idx];
            acc[b] += wv.x * qv.x + wv.y * qv.y + wv.z * qv.z + wv.w * qv.w;
        }
    }
    // wave-level reduce (wave64)
    #pragma unroll
    for (int b = 0; b < B; ++b) {
        float v = acc[b];
        #pragma unroll
        for (int off = 32; off > 0; off >>= 1) v += __shfl_down(v, off, 64);
        acc[b] = v;
    }
    int wave = t >> 6, lane = t & 63;
    if (lane == 0) {
        #pragma unroll
        for (int b = 0; b < B; ++b) wred[wave][b] = acc[b];
    }
    __syncthreads();
    if (t < B) {
        float s = wred[0][t] + wred[1][t] + wred[2][t] + wred[3][t] + b1[r];
        hws[(size_t)t * RH + r] = fmaxf(s, 0.0f);
    }
}

// ---------------------------------------------------------------------------
// K2c: fused gate (logits + wave-parallel top-k + softmax + sigmoid fold)
//      + contrib. grid = B * (H4/64) = 128 blocks, 64 threads (1 wave).
// Each block redundantly computes routing for its batch (cheap, parallel),
// then produces a 64-float4 slice of contrib.
// ---------------------------------------------------------------------------
__global__ __launch_bounds__(64) void k_gate_contrib(const float* __restrict__ hws,
                                                     const float* __restrict__ W2,
                                                     const float* __restrict__ b2,
                                                     const float* __restrict__ gate,
                                                     const float* __restrict__ memory,
                                                     const int* __restrict__ topk_p,
                                                     float* __restrict__ contrib) {
    __shared__ float lh[RH];      // hws row for this batch
    __shared__ float wf[64];      // folded weights: [k][m]

    int blk = blockIdx.x;
    int b   = blk / (H4 / 64);
    int ht  = blk % (H4 / 64);
    int lane = threadIdx.x;       // 0..63

    int K = topk_p[0];
    if (K > 8) K = 8;
    if (K < 1) K = 1;

    // stage hws[b][0..255] into LDS (64 lanes x float4)
    float4 hv = ((const float4*)hws)[(size_t)b * (RH / 4) + lane];
    lh[lane * 4 + 0] = hv.x; lh[lane * 4 + 1] = hv.y;
    lh[lane * 4 + 2] = hv.z; lh[lane * 4 + 3] = hv.w;
    __syncthreads();

    // logits: lane n owns slot n
    float logit;
    {
        const float4* w4 = (const float4*)W2 + (size_t)lane * (RH / 4);
        float acc = b2[lane];
        #pragma unroll 8
        for (int i = 0; i < RH / 4; ++i) {
            float4 wv = w4[i];
            acc += wv.x * lh[4 * i] + wv.y * lh[4 * i + 1] +
                   wv.z * lh[4 * i + 2] + wv.w * lh[4 * i + 3];
        }
        logit = acc;              // TEMP == 1.0
    }

    // wave-parallel top-8 (guarded by K at use sites); ties -> lowest index
    float v = logit;
    float tvals[8]; int tids[8];
    #pragma unroll
    for (int k = 0; k < 8; ++k) {
        float m = v; int mi = lane;
        #pragma unroll
        for (int off = 32; off > 0; off >>= 1) {
            float om = __shfl_xor(m, off, 64);
            int   oi = __shfl_xor(mi, off, 64);
            if (om > m || (om == m && oi < mi)) { m = om; mi = oi; }
        }
        tvals[k] = m; tids[k] = mi;
        if (lane == mi) v = -INFINITY;
    }

    // softmax over selected logits (uniform across lanes)
    float mx = tvals[0];
    float e[8]; float se = 0.f;
    #pragma unroll
    for (int k = 0; k < 8; ++k) {
        float ek = (k < K) ? expf(tvals[k] - mx) : 0.f;
        e[k] = ek; se += ek;
    }
    float inv = 1.0f / se;

    // fold: wf[k][m] = softmax_k * sigmoid(gate[slot_k][m]); lane = k*16+m
    {
        int k_of = lane >> 4, m_of = lane & 15;
        float wfv = 0.f;
        #pragma unroll
        for (int k = 0; k < 8; ++k) {
            if (k < K && k == k_of) {
                float g = gate[tids[k] * MEM + m_of];
                wfv = e[k] * inv / (1.0f + expf(-g));
            }
        }
        wf[lane] = wfv;
    }
    __syncthreads();

    // contrib slice: h4 = ht*64 + lane
    int h4 = ht * 64 + lane;
    float4 a = {0.f, 0.f, 0.f, 0.f};
    #pragma unroll
    for (int k = 0; k < 8; ++k) {
        if (k < K) {
            const float4* mp = (const float4*)memory + ((size_t)tids[k] * MEM) * H4 + h4;
            #pragma unroll
            for (int m = 0; m < MEM; ++m) {
                float w = wf[k * MEM + m];
                float4 vv = mp[(size_t)m * H4];
                a.x += w * vv.x; a.y += w * vv.y; a.z += w * vv.z; a.w += w * vv.w;
            }
        }
    }
    ((float4*)contrib)[(size_t)b * H4 + h4] = a;
}

// ---------------------------------------------------------------------------
// K3: out[b,s,h] = hidden[b,s,h] + contrib[b,h]   (float4 grid-stride)
// hidden/out streamed once -> nontemporal; contrib small -> cached.
// ---------------------------------------------------------------------------
__global__ __launch_bounds__(256) void k_add(const float* __restrict__ hidden,
                                             const float* __restrict__ contrib,
                                             float* __restrict__ out) {
    const size_t total4 = (size_t)B * S * H4;      // 16,777,216
    const size_t stride = (size_t)gridDim.x * blockDim.x;
    const float4* hv4 = (const float4*)hidden;
    const float4* cv4 = (const float4*)contrib;
    float4* o4 = (float4*)out;
    for (size_t i = (size_t)blockIdx.x * blockDim.x + threadIdx.x; i < total4; i += stride) {
        int h4 = (int)(i & (size_t)(H4 - 1));      // H4 = 1024 (pow2)
        int b  = (int)(i >> 21);                   // S*H4 = 2^21 per batch
        float4 hv = ntload4(&hv4[i]);
        float4 cv = cv4[(size_t)b * H4 + h4];
        float4 o  = {hv.x + cv.x, hv.y + cv.y, hv.z + cv.z, hv.w + cv.w};
        ntstore4(&o4[i], o);
    }
}

// ---------------------------------------------------------------------------
extern "C" void kernel_launch(void* const* d_in, const int* in_sizes, int n_in,
                              void* d_out, int out_size, void* d_ws, size_t ws_size,
                              hipStream_t stream) {
    const float* embeds = (const float*)d_in[0];
    const float* hidden = (const float*)d_in[1];
    const float* W1     = (const float*)d_in[2];
    const float* b1     = (const float*)d_in[3];
    const float* W2     = (const float*)d_in[4];
    const float* b2     = (const float*)d_in[5];
    const float* gate   = (const float*)d_in[6];
    const float* memory = (const float*)d_in[7];
    const int*   topk   = (const int*)d_in[8];
    float* out = (float*)d_out;

    // workspace layout (floats)
    float* partial = (float*)d_ws;                        // B*SCHUNK*H = 524288 (2 MB)
    float* q       = partial + (size_t)B * SCHUNK * H;    // B*H        = 32768
    float* hws     = q       + (size_t)B * H;             // B*RH       = 2048
    float* contrib = hws     + (size_t)B * RH;            // B*H        = 32768

    k_partial     <<<dim3(B * (H4 / 256) * SCHUNK), dim3(256), 0, stream>>>(embeds, partial);
    k_mean        <<<dim3(B * H4 / 256),            dim3(256), 0, stream>>>(partial, q);
    k_w1          <<<dim3(RH),                      dim3(256), 0, stream>>>(q, W1, b1, hws);
    k_gate_contrib<<<dim3(B * (H4 / 64)),           dim3(64),  0, stream>>>(hws, W2, b2, gate,
                                                                            memory, topk, contrib);
    k_add         <<<dim3(4096),                    dim3(256), 0, stream>>>(hidden, contrib, out);
}